// Round 10
// baseline (723.374 us; speedup 1.0000x reference)
//
#include <hip/hip_runtime.h>
#include <hip/hip_bf16.h>
#include <stdint.h>

// Problem constants (B,S,D,H fixed by the reference)
constexpr int kB  = 4;
constexpr int kS  = 2048;
constexpr int kD  = 1024;
constexpr int kH  = 16;
constexpr int kDH = 64;
constexpr int kM  = kB * kS;     // 8192
constexpr int k3D = 3 * kD;      // 3072

// 0.125 (1/sqrt(DH)) * log2(e): scores leave GEMM1 in log2 domain -> exp2
constexpr float kQscale = 0.18033688011112042f;

typedef __attribute__((ext_vector_type(8))) short short8;  // 8 bf16 (4 VGPRs)
typedef __attribute__((ext_vector_type(4))) float f32x4;   // MFMA C/D

__device__ __forceinline__ float exp2v(float x) {
  return __builtin_amdgcn_exp2f(x);   // v_exp_f32 (base-2)
}

__device__ __forceinline__ unsigned short f2bf(float f) {
  unsigned u = __float_as_uint(f);
  u += 0x7fffu + ((u >> 16) & 1u);   // RNE
  return (unsigned short)(u >> 16);
}

// packed f32x2 -> bf16x2 (low = lo), single HW instr (T12 primitive)
__device__ __forceinline__ unsigned cvtpk2bf(float lo, float hi) {
  unsigned r;
  asm("v_cvt_pk_bf16_f32 %0, %1, %2" : "=v"(r) : "v"(lo), "v"(hi));
  return r;
}

// async global->LDS, 16B per lane. LDS dest must be wave-uniform base + lane*16.
__device__ __forceinline__ void async16(const void* g, void* l) {
  __builtin_amdgcn_global_load_lds(
      (const __attribute__((address_space(1))) unsigned int*)g,
      (__attribute__((address_space(3))) unsigned int*)l, 16, 0, 0);
}

// ---------------------------------------------------------------------------
// fp32 -> bf16 convert for all three inputs in one launch
// ---------------------------------------------------------------------------
__global__ __launch_bounds__(256) void cvt_bf16_3(
    const float* __restrict__ x, const float* __restrict__ wi,
    const float* __restrict__ wo, unsigned short* __restrict__ xb,
    unsigned short* __restrict__ wib, unsigned short* __restrict__ wob) {
  constexpr int n_x  = kM * kD / 4;
  constexpr int n_wi = k3D * kD / 4;
  int i = blockIdx.x * 256 + threadIdx.x;
  const float* src;
  unsigned short* dst;
  int j;
  if (i < n_x)            { src = x;  dst = xb;  j = i; }
  else if (i < n_x + n_wi){ src = wi; dst = wib; j = i - n_x; }
  else                    { src = wo; dst = wob; j = i - n_x - n_wi; }
  float4 v = ((const float4*)src)[j];
  ushort4 r;
  r.x = f2bf(v.x); r.y = f2bf(v.y); r.z = f2bf(v.z); r.w = f2bf(v.w);
  ((ushort4*)dst)[j] = r;
}

// ---------------------------------------------------------------------------
// 256x256 MFMA GEMM, BK=32, BARRIER-LIGHT (round-10).
// Same 256^2 tile / 8-wave 2Mx4N / barrier-light schedule as the verified
// round-7 kernel, but BK halved 64->32: LDS 128->64 KB -> 2 blocks/CU.
// All 384 blocks co-resident (no 1.5-round tail) and the per-K-tile
// vmcnt(0) drain is covered by the OTHER block on the CU (m114 overlap).
// T2 swizzle re-derived for 4-chunk rows: store c = c_lin ^ (r&3); frag
// read chunk = quad ^ (l15&3)  (bank-balanced: 8 lanes per 4-bank cluster
// = the 8-cycle minimum for a 1KB ds_read_b128).
// FUSED V-TRANSPOSE EPILOGUE (VT=true): V-column blocks (col0 >= 2048)
// write transposed straight to vtb via the 64 KB LDS in TWO 128-column
// passes; qkvb write skipped.
// QSCALE: multiply (acc+bias) by kQscale for output cols < kD (Q columns).
// ---------------------------------------------------------------------------
template <bool OUT_BF16, bool QSCALE, bool VT>
__global__ __launch_bounds__(512, 4) void gemm_mfma_256(
    const unsigned short* __restrict__ A, int lda,
    const unsigned short* __restrict__ Bt, int ldb,
    const float* __restrict__ bias, void* __restrict__ Cp, int ldc, int K,
    unsigned short* __restrict__ vtbp) {
  __shared__ unsigned short SL[32768];  // 64 KB: A dbuf | B dbuf; VT reuses
  auto Asl = (unsigned short(*)[8192])(SL);           // 2 x 16 KB
  auto Bsl = (unsigned short(*)[8192])(SL + 16384);   // 2 x 16 KB
  const int t = threadIdx.x;
  const int lane = t & 63, l15 = lane & 15, quad = lane >> 4, w = t >> 6;

  // Bijective XCD swizzle (grid has nwg % 8 == 0; guarded anyway)
  const int nwg = gridDim.x * gridDim.y;
  int bid = blockIdx.y * gridDim.x + blockIdx.x;
  if ((nwg & 7) == 0) bid = (bid & 7) * (nwg >> 3) + (bid >> 3);
  const int bx = bid % gridDim.x, by = bid / gridDim.x;
  const int row0 = by * 256, col0 = bx * 256;
  const int wm = (w & 1) * 128, wn = (w >> 1) * 64;

  f32x4 acc[8][4] = {};  // [mq*4+mt][nq*2+nt]

  // Staging: per K-tile each operand = 256 rows x 32 cols = 1024 chunks of
  // 16B (4 chunks/row) = 2 chunks/thread. slot s -> r = s>>2, c_lin = s&3;
  // stored logical chunk c = c_lin ^ (r&3) (involution). LDS dest linear.
  const unsigned short* gA[2];
  const unsigned short* gB[2];
#pragma unroll
  for (int ss = 0; ss < 2; ++ss) {
    const int s = t + ss * 512;
    const int r = s >> 2, c = (s & 3) ^ (r & 3);
    gA[ss] = A  + (size_t)(row0 + r) * lda + c * 8;
    gB[ss] = Bt + (size_t)(col0 + r) * ldb + c * 8;
  }

#define STG_ALL(buf, k0)                                       \
  do {                                                         \
    async16(gA[0] + (k0), Asl[buf] + t * 8);                   \
    async16(gA[1] + (k0), Asl[buf] + (t + 512) * 8);           \
    async16(gB[0] + (k0), Bsl[buf] + t * 8);                   \
    async16(gB[1] + (k0), Bsl[buf] + (t + 512) * 8);           \
  } while (0)

  // Frag reads: row*32 shorts (64B/row), chunk quad ^ (l15&3).
  // (wm, mq*64, mt*16, wn, nq*32, nt*16 are all multiples of 4.)
#define ARD(mq, mt)                                                      \
  (*(const short8*)(as + (wm + (mq) * 64 + (mt) * 16 + l15) * 32 +       \
                    (((quad) ^ (l15 & 3)) * 8)))
#define BRD(nq, nt)                                                      \
  (*(const short8*)(bs + (wn + (nq) * 32 + (nt) * 16 + l15) * 32 +       \
                    (((quad) ^ (l15 & 3)) * 8)))

  const int nkt = K / 32;  // 32 here
  STG_ALL(0, 0);           // prologue: K-tile 0 into slot 0

  short8 af[2][4];
  short8 bf[2][2];

  for (int kt = 0; kt < nkt; ++kt) {
    const int buf = kt & 1, nbuf = buf ^ 1;
    const int k0n = (kt + 1) * 32;
    const bool pf = (kt + 1 < nkt);
    const unsigned short* as = Asl[buf];
    const unsigned short* bs = Bsl[buf];

    // ONE sync point per K-tile. (All waves' reads of buf(kt-1) precede
    // their arrival here, so the stages into nbuf below are race-free.)
    asm volatile("s_waitcnt vmcnt(0)" ::: "memory");
    __builtin_amdgcn_s_barrier();
    __builtin_amdgcn_sched_barrier(0);  // no ds_read hoisted above barrier

    if (pf) STG_ALL(nbuf, k0n);  // next tile: full-iteration cover

    // ---- P1: quadrant (0,0) ----------------------------------------------
#pragma unroll
    for (int mt = 0; mt < 4; ++mt) af[0][mt] = ARD(0, mt);
#pragma unroll
    for (int nt = 0; nt < 2; ++nt) bf[0][nt] = BRD(0, nt);
    __builtin_amdgcn_s_setprio(1);
#pragma unroll
    for (int mt = 0; mt < 4; ++mt)
#pragma unroll
      for (int nt = 0; nt < 2; ++nt)
        acc[mt][nt] = __builtin_amdgcn_mfma_f32_16x16x32_bf16(
            af[0][mt], bf[0][nt], acc[mt][nt], 0, 0, 0);
    __builtin_amdgcn_s_setprio(0);

    // ---- P2: quadrant (1,0) ----------------------------------------------
#pragma unroll
    for (int mt = 0; mt < 4; ++mt) af[1][mt] = ARD(1, mt);
    __builtin_amdgcn_s_setprio(1);
#pragma unroll
    for (int mt = 0; mt < 4; ++mt)
#pragma unroll
      for (int nt = 0; nt < 2; ++nt)
        acc[4 + mt][nt] = __builtin_amdgcn_mfma_f32_16x16x32_bf16(
            af[1][mt], bf[0][nt], acc[4 + mt][nt], 0, 0, 0);
    __builtin_amdgcn_s_setprio(0);

    // ---- P3: quadrant (1,1) ----------------------------------------------
#pragma unroll
    for (int nt = 0; nt < 2; ++nt) bf[1][nt] = BRD(1, nt);
    __builtin_amdgcn_s_setprio(1);
#pragma unroll
    for (int mt = 0; mt < 4; ++mt)
#pragma unroll
      for (int nt = 0; nt < 2; ++nt)
        acc[4 + mt][2 + nt] = __builtin_amdgcn_mfma_f32_16x16x32_bf16(
            af[1][mt], bf[1][nt], acc[4 + mt][2 + nt], 0, 0, 0);
    __builtin_amdgcn_s_setprio(0);

    // ---- P4: quadrant (0,1) ----------------------------------------------
    __builtin_amdgcn_s_setprio(1);
#pragma unroll
    for (int mt = 0; mt < 4; ++mt)
#pragma unroll
      for (int nt = 0; nt < 2; ++nt)
        acc[mt][2 + nt] = __builtin_amdgcn_mfma_f32_16x16x32_bf16(
            af[0][mt], bf[1][nt], acc[mt][2 + nt], 0, 0, 0);
    __builtin_amdgcn_s_setprio(0);
  }
#undef STG_ALL
#undef ARD
#undef BRD

  float bv[4];
#pragma unroll
  for (int n = 0; n < 4; ++n)
    bv[n] = bias[col0 + wn + (n >> 1) * 32 + (n & 1) * 16 + l15];

  if (VT && col0 >= 2 * kD) {
    // ---- fused V-transpose epilogue: C^T -> vtb via 64 KB SL, 2 passes ---
    // acc[m][n][i]: r_local = wm + (m>>2)*64 + (m&3)*16 + quad*4 + i (s dim)
    //               cl      = wn + (n>>1)*32 + (n&1)*16 + l15        (d dim)
    // Pass p handles cl in [128p, 128p+128): SL row (cl-128p) of 512 B
    // (256 s-values), 8B units u = r_local>>2 swizzled u ^ (cl&15).
    const int b_ = by >> 3, s0 = (by & 7) * 256;
    const int lhalf = lane >> 5, l31 = lane & 31;
#pragma unroll
    for (int p = 0; p < 2; ++p) {
      __syncthreads();  // K-loop reads done (p=0) / prev pass stores done
      if ((w >> 2) == p) {  // waves whose cl-range falls in this pass
#pragma unroll
        for (int m = 0; m < 8; ++m)
#pragma unroll
          for (int n = 0; n < 4; ++n) {
            const int clp =
                (wn - p * 128) + (n >> 1) * 32 + (n & 1) * 16 + l15;
            const int u = (wm >> 2) + (m >> 2) * 16 + (m & 3) * 4 + quad;
            uint2 pk = make_uint2(
                cvtpk2bf(acc[m][n][0] + bv[n], acc[m][n][1] + bv[n]),
                cvtpk2bf(acc[m][n][2] + bv[n], acc[m][n][3] + bv[n]));
            *(uint2*)(SL + clp * 256 + ((u ^ (clp & 15)) << 2)) = pk;
          }
      }
      __syncthreads();
      // stream out: half-wave per d-row -> coalesced 512B row segments
#pragma unroll
      for (int ps = 0; ps < 8; ++ps) {
        const int clp = ps * 16 + w * 2 + lhalf;  // 0..127
        uint2 v0 = *(const uint2*)(SL + clp * 256 +
                                   (((l31 * 2) ^ (clp & 15)) << 2));
        uint2 v1 = *(const uint2*)(SL + clp * 256 +
                                   (((l31 * 2 + 1) ^ (clp & 15)) << 2));
        uint4 vv = make_uint4(v0.x, v0.y, v1.x, v1.y);
        unsigned short* gd =
            vtbp + (size_t)(b_ * 1024 + col0 - 2 * kD + p * 128 + clp) * kS +
            s0 + l31 * 8;
        *(uint4*)gd = vv;
      }
    }
    return;
  }

  const float sc = (QSCALE && col0 < kD) ? kQscale : 1.0f;
#pragma unroll
  for (int m = 0; m < 8; ++m)
#pragma unroll
    for (int i = 0; i < 4; ++i) {
      const size_t r =
          (size_t)(row0 + wm + (m >> 2) * 64 + (m & 3) * 16 + quad * 4 + i);
#pragma unroll
      for (int n = 0; n < 4; ++n) {
        float v = (acc[m][n][i] + bv[n]) * sc;
        const size_t cidx =
            r * (size_t)ldc + col0 + wn + (n >> 1) * 32 + (n & 1) * 16 + l15;
        if (OUT_BF16) ((unsigned short*)Cp)[cidx] = f2bf(v);
        else          ((float*)Cp)[cidx] = v;
      }
    }
}

// ---------------------------------------------------------------------------
// 128x128 / BK=32 / 256-thread MFMA GEMM — round-0 version, verified passing.
// ---------------------------------------------------------------------------
template <bool OUT_BF16, bool QSCALE>
__global__ __launch_bounds__(256) void gemm_mfma_128(
    const unsigned short* __restrict__ A, int lda,
    const unsigned short* __restrict__ Bt, int ldb,
    const float* __restrict__ bias, void* __restrict__ Cp, int ldc, int K) {
  __shared__ unsigned short As[2][4096];  // 16 KB
  __shared__ unsigned short Bs[2][4096];  // 16 KB
  const int t = threadIdx.x;
  const int lane = t & 63, l15 = lane & 15, quad = lane >> 4, w = t >> 6;

  const int nwg = gridDim.x * gridDim.y;
  int bid = blockIdx.y * gridDim.x + blockIdx.x;
  if ((nwg & 7) == 0) bid = (bid & 7) * (nwg >> 3) + (bid >> 3);
  const int bx = bid % gridDim.x, by = bid / gridDim.x;

  const int row0 = by * 128, col0 = bx * 128;
  const int wm = (w & 1) * 64, wn = (w >> 1) * 64;

  f32x4 acc[4][4] = {};

  const int q1 = t, q2 = t + 256;
  const unsigned short* a1 = A  + (size_t)(row0 + (q1 & 127)) * lda + (q1 >> 7) * 8;
  const unsigned short* a2 = A  + (size_t)(row0 + (q2 & 127)) * lda + (q2 >> 7) * 8;
  const unsigned short* b1 = Bt + (size_t)(col0 + (q1 & 127)) * ldb + (q1 >> 7) * 8;
  const unsigned short* b2 = Bt + (size_t)(col0 + (q2 & 127)) * ldb + (q2 >> 7) * 8;

  const int nIter = K / 32;
  async16(a1, As[0] + q1 * 8);
  async16(a2, As[0] + q2 * 8);
  async16(b1, Bs[0] + q1 * 8);
  async16(b2, Bs[0] + q2 * 8);

  for (int it = 0; it < nIter; ++it) {
    __syncthreads();
    const int cb = it & 1, nb = cb ^ 1;
    if (it + 1 < nIter) {
      const int k0 = (it + 1) * 32;
      async16(a1 + k0, As[nb] + q1 * 8);
      async16(a2 + k0, As[nb] + q2 * 8);
      async16(b1 + k0, Bs[nb] + q1 * 8);
      async16(b2 + k0, Bs[nb] + q2 * 8);
    }
    short8 af[4], bf[4];
#pragma unroll
    for (int mt = 0; mt < 4; ++mt)
      af[mt] = *(const short8*)(As[cb] + (quad * 128 + wm + mt * 16 + l15) * 8);
#pragma unroll
    for (int nt = 0; nt < 4; ++nt)
      bf[nt] = *(const short8*)(Bs[cb] + (quad * 128 + wn + nt * 16 + l15) * 8);
#pragma unroll
    for (int mt = 0; mt < 4; ++mt)
#pragma unroll
      for (int nt = 0; nt < 4; ++nt)
        acc[mt][nt] = __builtin_amdgcn_mfma_f32_16x16x32_bf16(
            af[mt], bf[nt], acc[mt][nt], 0, 0, 0);
  }

  const float sc = (QSCALE && col0 < kD) ? kQscale : 1.0f;
  float bv[4];
#pragma unroll
  for (int nt = 0; nt < 4; ++nt) bv[nt] = bias[col0 + wn + nt * 16 + l15];
#pragma unroll
  for (int mt = 0; mt < 4; ++mt)
#pragma unroll
    for (int i = 0; i < 4; ++i) {
      const size_t r = (size_t)(row0 + wm + mt * 16 + quad * 4 + i);
#pragma unroll
      for (int nt = 0; nt < 4; ++nt) {
        float v = (acc[mt][nt][i] + bv[nt]) * sc;
        const size_t cidx = r * (size_t)ldc + col0 + wn + nt * 16 + l15;
        if (OUT_BF16) ((unsigned short*)Cp)[cidx] = f2bf(v);
        else          ((float*)Cp)[cidx] = v;
      }
    }
}

// ---------------------------------------------------------------------------
// MFMA flash attention (round-7 version, verified at 87.5 us):
// S^T formulation, register-Q, pair-balanced; XCD-group swizzle (K/V of one
// (b,h) co-located per XCD L2); double-buffered K AND V with one barrier per
// k-tile; cvt_pk P-store; defer-max; setprio around MFMA.
// ---------------------------------------------------------------------------
__global__ __launch_bounds__(256, 4) void flash_attn_mfma(
    unsigned short* __restrict__ qkvb, const unsigned short* __restrict__ vtb,
    const int* __restrict__ cflag) {
  __shared__ unsigned short QP[4096];     // Q then P buffer            8 KB
  __shared__ unsigned short Ks[2][4096];  // K double buffer           16 KB
  __shared__ unsigned short Vt[2][4096];  // V double buffer           16 KB

  const int lin = blockIdx.x;
  const int pr = lin >> 6;                          // 0..15 (pair id)
  const int g  = ((lin >> 3) & 7) * 8 + (lin & 7);  // 0..63
  const int h = g & 15, b = g >> 4;
  const int t = threadIdx.x;
  const int lane = t & 63, l15 = lane & 15, quad = lane >> 4, w = t >> 6;
  const bool causal = (*cflag) != 0;

  unsigned short* qbase = qkvb + (size_t)(b * kS) * k3D + h * kDH;
  const unsigned short* vbase = vtb + (size_t)((b * kH + h) * kDH) * kS;
  const int c0 = t, c1 = t + 256;

  for (int half = 0; half < 2; ++half) {
    const int qt = half ? (31 - pr) : pr;
    const int q0 = qt * 64;
    const int ntiles = causal ? (qt + 1) : 32;

    // ---- prologue: stage Q + K0 + V0 (all into buffer 0)
    async16(qbase + (size_t)(q0 + (c0 & 63)) * k3D + (c0 >> 6) * 8, QP + c0 * 8);
    async16(qbase + (size_t)(q0 + (c1 & 63)) * k3D + (c1 >> 6) * 8, QP + c1 * 8);
    async16(qbase + kD + (size_t)(c0 & 63) * k3D + (c0 >> 6) * 8, Ks[0] + c0 * 8);
    async16(qbase + kD + (size_t)(c1 & 63) * k3D + (c1 >> 6) * 8, Ks[0] + c1 * 8);
    async16(vbase + (size_t)(c0 & 63) * kS + (c0 >> 6) * 8, Vt[0] + c0 * 8);
    async16(vbase + (size_t)(c1 & 63) * kS + (c1 >> 6) * 8, Vt[0] + c1 * 8);
    __syncthreads();  // drains Q + K0 + V0

    // hoist Q fragments to registers — QP becomes the P buffer afterwards
    short8 bq[2];
#pragma unroll
    for (int kf = 0; kf < 2; ++kf)
      bq[kf] = *(const short8*)(
          QP + ((kf * 4 + quad) * 64 + w * 16 + l15) * 8);

    f32x4 O[4] = {};                  // [d-tile ntd]; q row = w*16+quad*4+i
    float m_i = -3.0e38f, l_i = 0.f;  // per q (q = w*16+l15)

    for (int kt = 0; kt < ntiles; ++kt) {
      const int cb = kt & 1, nb = cb ^ 1;
      const int kk0 = kt * 64;

      // ---- issue K/V(kt+1) into spare buffer: full-iteration cover
      if (kt + 1 < ntiles) {
        const int kn = kk0 + 64;
        async16(qbase + kD + (size_t)(kn + (c0 & 63)) * k3D + (c0 >> 6) * 8,
                Ks[nb] + c0 * 8);
        async16(qbase + kD + (size_t)(kn + (c1 & 63)) * k3D + (c1 >> 6) * 8,
                Ks[nb] + c1 * 8);
        async16(vbase + (size_t)(c0 & 63) * kS + kn + (c0 >> 6) * 8,
                Vt[nb] + c0 * 8);
        async16(vbase + (size_t)(c1 & 63) * kS + kn + (c1 >> 6) * 8,
                Vt[nb] + c1 * 8);
      }

      // ---- S^T = K·Q^T: key = kk0+mt*16+quad*4+reg, q = w*16+l15
      f32x4 s[4];
      __builtin_amdgcn_s_setprio(1);
#pragma unroll
      for (int mt = 0; mt < 4; ++mt) {
        short8 a0 = *(const short8*)(Ks[cb] + ((quad)*64 + mt * 16 + l15) * 8);
        short8 a1 =
            *(const short8*)(Ks[cb] + ((4 + quad) * 64 + mt * 16 + l15) * 8);
        f32x4 z = {};
        z = __builtin_amdgcn_mfma_f32_16x16x32_bf16(a0, bq[0], z, 0, 0, 0);
        z = __builtin_amdgcn_mfma_f32_16x16x32_bf16(a1, bq[1], z, 0, 0, 0);
        s[mt] = z;
      }
      __builtin_amdgcn_s_setprio(0);

      // ---- online softmax (scores in log2 domain; diagonal tile masked)
      const int gq = q0 + w * 16 + l15;
      if (causal && kt == ntiles - 1) {
#pragma unroll
        for (int mt = 0; mt < 4; ++mt)
#pragma unroll
          for (int i = 0; i < 4; ++i)
            if (kk0 + mt * 16 + quad * 4 + i > gq) s[mt][i] = -3.0e38f;
      }
      float mx = -3.0e38f;
#pragma unroll
      for (int mt = 0; mt < 4; ++mt)
#pragma unroll
        for (int i = 0; i < 4; ++i) mx = fmaxf(mx, s[mt][i]);
      mx = fmaxf(mx, __shfl_xor(mx, 16));
      mx = fmaxf(mx, __shfl_xor(mx, 32));

      // defer-max (T13): only rescale when the running max grew by > 8
      if (!__all(mx <= m_i + 8.0f)) {
        const float mn = fmaxf(m_i, mx);
        const float alpha = exp2v(m_i - mn);
        m_i = mn;
        l_i *= alpha;
#pragma unroll
        for (int i = 0; i < 4; ++i) {
          const float a = __shfl(alpha, quad * 4 + i);
#pragma unroll
          for (int ntd = 0; ntd < 4; ++ntd) O[ntd][i] *= a;
        }
      }

      float p[4][4];
      float rs = 0.f;
#pragma unroll
      for (int mt = 0; mt < 4; ++mt)
#pragma unroll
        for (int i = 0; i < 4; ++i) {
          p[mt][i] = exp2v(s[mt][i] - m_i);
          rs += p[mt][i];
        }
      rs += __shfl_xor(rs, 16);
      rs += __shfl_xor(rs, 32);
      l_i += rs;

      // packed P store via v_cvt_pk_bf16_f32: 4 consecutive keys at row gq
#pragma unroll
      for (int mt = 0; mt < 4; ++mt) {
        uint2 pk = make_uint2(cvtpk2bf(p[mt][0], p[mt][1]),
                              cvtpk2bf(p[mt][2], p[mt][3]));
        *(uint2*)(QP + ((mt * 2 + (quad >> 1)) * 64 + w * 16 + l15) * 8 +
                  (quad & 1) * 4) = pk;
      }

      // ---- O += P·V (P rows wave-private; compiler orders write->read)
      __builtin_amdgcn_s_setprio(1);
#pragma unroll
      for (int kf = 0; kf < 2; ++kf) {
        short8 aP = *(const short8*)(
            QP + ((kf * 4 + quad) * 64 + w * 16 + l15) * 8);
#pragma unroll
        for (int ntd = 0; ntd < 4; ++ntd) {
          short8 bV = *(const short8*)(
              Vt[cb] + ((kf * 4 + quad) * 64 + ntd * 16 + l15) * 8);
          O[ntd] = __builtin_amdgcn_mfma_f32_16x16x32_bf16(
              aP, bV, O[ntd], 0, 0, 0);
        }
      }
      __builtin_amdgcn_s_setprio(0);

      // single barrier per k-tile: reads of buffer cb done + K/V(kt+1) landed
      __syncthreads();
    }

    // ---- epilogue: /l, bf16, overwrite own Q slots
#pragma unroll
    for (int i = 0; i < 4; ++i) {
      const float linv = 1.0f / __shfl(l_i, quad * 4 + i);
      unsigned short* dst =
          qbase + (size_t)(q0 + w * 16 + quad * 4 + i) * k3D;
#pragma unroll
      for (int ntd = 0; ntd < 4; ++ntd)
        dst[ntd * 16 + l15] = f2bf(O[ntd][i] * linv);
    }
  }
}

// ---------------------------------------------------------------------------
extern "C" void kernel_launch(void* const* d_in, const int* in_sizes, int n_in,
                              void* d_out, int out_size, void* d_ws,
                              size_t ws_size, hipStream_t stream) {
  const float* x     = (const float*)d_in[0];
  const float* w_in  = (const float*)d_in[1];
  const float* b_in  = (const float*)d_in[2];
  const float* w_out = (const float*)d_in[3];
  const float* b_out = (const float*)d_in[4];
  const int*   cfl   = (const int*)d_in[5];
  float* out = (float*)d_out;

  // workspace layout (all 16B-aligned), total 92.3 MB
  char* ws = (char*)d_ws;
  unsigned short* qkvb = (unsigned short*)(ws);              // 8192x3072 bf16 = 48 MB
  unsigned short* xb   = (unsigned short*)(ws + 50331648);   // 8192x1024 bf16 = 16 MB
  unsigned short* wib  = (unsigned short*)(ws + 67108864);   // 3072x1024 bf16 =  6 MB
  unsigned short* wob  = (unsigned short*)(ws + 73400320);   // 1024x1024 bf16 =  2 MB
  unsigned short* vtb  = (unsigned short*)(ws + 75497472);   // [b,h,d,s] bf16 = 16 MB

  // 0) all three fp32->bf16 conversions in one launch
  cvt_bf16_3<<<(kM * kD + k3D * kD + kD * kD) / 4 / 256, 256, 0, stream>>>(
      x, w_in, w_out, xb, wib, wob);

  // 1) qkv = x @ w_in^T + b_in (bf16 out; Q cols pre-scaled by 0.125*log2e).
  //    BK=32, 64 KB LDS -> 2 blocks/CU, all 384 blocks co-resident.
  //    V-column blocks write TRANSPOSED directly to vtb (fused v_transpose).
  gemm_mfma_256<true, true, true><<<dim3(k3D / 256, kM / 256), 512, 0, stream>>>(
      xb, kD, wib, kD, b_in, qkvb, k3D, kD, vtb);

  // 2) flash attention (pair-balanced, XCD-grouped, double-buffered K/V)
  flash_attn_mfma<<<dim3(16 * kH * kB), 256, 0, stream>>>(qkvb, vtb, cfl);

  // 3) out = attn @ w_out^T + b_out (fp32 out; A rows inside qkvb, lda=3072)
  gemm_mfma_128<false, false><<<dim3(kD / 128, kM / 128), 256, 0, stream>>>(
      qkvb, k3D, wob, kD, b_out, out, kD, kD);
}

// Round 11
// 256.180 us; speedup vs baseline: 2.8237x; 2.8237x over previous
//
#include <hip/hip_runtime.h>
#include <hip/hip_bf16.h>
#include <stdint.h>

// Problem constants (B,S,D,H fixed by the reference)
constexpr int kB  = 4;
constexpr int kS  = 2048;
constexpr int kD  = 1024;
constexpr int kH  = 16;
constexpr int kDH = 64;
constexpr int kM  = kB * kS;     // 8192
constexpr int k3D = 3 * kD;      // 3072

// 0.125 (1/sqrt(DH)) * log2(e): scores leave GEMM1 in log2 domain -> exp2
constexpr float kQscale = 0.18033688011112042f;

typedef __attribute__((ext_vector_type(8))) short short8;  // 8 bf16 (4 VGPRs)
typedef __attribute__((ext_vector_type(4))) float f32x4;   // MFMA C/D

__device__ __forceinline__ float exp2v(float x) {
  return __builtin_amdgcn_exp2f(x);   // v_exp_f32 (base-2)
}

__device__ __forceinline__ unsigned short f2bf(float f) {
  unsigned u = __float_as_uint(f);
  u += 0x7fffu + ((u >> 16) & 1u);   // RNE
  return (unsigned short)(u >> 16);
}

// packed f32x2 -> bf16x2 (low = lo), single HW instr (T12 primitive)
__device__ __forceinline__ unsigned cvtpk2bf(float lo, float hi) {
  unsigned r;
  asm("v_cvt_pk_bf16_f32 %0, %1, %2" : "=v"(r) : "v"(lo), "v"(hi));
  return r;
}

// async global->LDS, 16B per lane. LDS dest must be wave-uniform base + lane*16.
__device__ __forceinline__ void async16(const void* g, void* l) {
  __builtin_amdgcn_global_load_lds(
      (const __attribute__((address_space(1))) unsigned int*)g,
      (__attribute__((address_space(3))) unsigned int*)l, 16, 0, 0);
}

// ---------------------------------------------------------------------------
// fp32 -> bf16 convert for all three inputs in one launch
// ---------------------------------------------------------------------------
__global__ __launch_bounds__(256) void cvt_bf16_3(
    const float* __restrict__ x, const float* __restrict__ wi,
    const float* __restrict__ wo, unsigned short* __restrict__ xb,
    unsigned short* __restrict__ wib, unsigned short* __restrict__ wob) {
  constexpr int n_x  = kM * kD / 4;
  constexpr int n_wi = k3D * kD / 4;
  int i = blockIdx.x * 256 + threadIdx.x;
  const float* src;
  unsigned short* dst;
  int j;
  if (i < n_x)            { src = x;  dst = xb;  j = i; }
  else if (i < n_x + n_wi){ src = wi; dst = wib; j = i - n_x; }
  else                    { src = wo; dst = wob; j = i - n_x - n_wi; }
  float4 v = ((const float4*)src)[j];
  ushort4 r;
  r.x = f2bf(v.x); r.y = f2bf(v.y); r.z = f2bf(v.z); r.w = f2bf(v.w);
  ((ushort4*)dst)[j] = r;
}

// ---------------------------------------------------------------------------
// 256x256 MFMA GEMM, BK=64, BARRIER-LIGHT (round-9 version, verified at
// 271.2 us total; G1 < 87 us). 128 KB LDS, __launch_bounds__(512,2) —
// NOTE: this tile is intrinsically 1 block/CU: acc[8][4] = 128 VGPR alone,
// ~250 regs/wave total -> 2 waves/SIMD. (512,4) caps at 128 VGPR -> full
// accumulator spill (round-10, 1.39 GB WRITE). Do not raise the bound.
// FUSED V-TRANSPOSE EPILOGUE (VT=true): V-column blocks (col0 >= 2048)
// write transposed straight to vtb via the 128 KB LDS; qkvb write skipped.
// QSCALE: multiply (acc+bias) by kQscale for output cols < kD (Q columns).
// ---------------------------------------------------------------------------
template <bool OUT_BF16, bool QSCALE, bool VT>
__global__ __launch_bounds__(512, 2) void gemm_mfma_256(
    const unsigned short* __restrict__ A, int lda,
    const unsigned short* __restrict__ Bt, int ldb,
    const float* __restrict__ bias, void* __restrict__ Cp, int ldc, int K,
    unsigned short* __restrict__ vtbp) {
  __shared__ unsigned short SL[65536];  // 128 KB: A dbuf | B dbuf; VT reuses
  auto Asl = (unsigned short(*)[16384])(SL);           // 2 x 32 KB
  auto Bsl = (unsigned short(*)[16384])(SL + 32768);   // 2 x 32 KB
  const int t = threadIdx.x;
  const int lane = t & 63, l15 = lane & 15, quad = lane >> 4, w = t >> 6;

  const int nwg = gridDim.x * gridDim.y;
  int bid = blockIdx.y * gridDim.x + blockIdx.x;
  if ((nwg & 7) == 0) bid = (bid & 7) * (nwg >> 3) + (bid >> 3);
  const int bx = bid % gridDim.x, by = bid / gridDim.x;
  const int row0 = by * 256, col0 = bx * 256;
  const int wm = (w & 1) * 128, wn = (w >> 1) * 64;

  f32x4 acc[8][4] = {};  // [mq*4+mt][nq*2+nt]

  const unsigned short* gA[2][2];
  const unsigned short* gB[2][2];
#pragma unroll
  for (int h = 0; h < 2; ++h)
#pragma unroll
    for (int ss = 0; ss < 2; ++ss) {
      const int s = t + ss * 512;
      const int r = s >> 3, c = (s & 7) ^ (r & 7);
      gA[h][ss] = A  + (size_t)(row0 + h * 128 + r) * lda + c * 8;
      gB[h][ss] = Bt + (size_t)(col0 + h * 128 + r) * ldb + c * 8;
    }

#define STG_A(h, buf, k0)                                              \
  do {                                                                 \
    async16(gA[h][0] + (k0), Asl[buf] + (h) * 8192 + t * 8);           \
    async16(gA[h][1] + (k0), Asl[buf] + (h) * 8192 + (t + 512) * 8);   \
  } while (0)
#define STG_B(h, buf, k0)                                              \
  do {                                                                 \
    async16(gB[h][0] + (k0), Bsl[buf] + (h) * 8192 + t * 8);           \
    async16(gB[h][1] + (k0), Bsl[buf] + (h) * 8192 + (t + 512) * 8);   \
  } while (0)

#define ARD(mq, mt, ks)                                                  \
  (*(const short8*)(as + (wm + (mq) * 64 + (mt) * 16 + l15) * 64 +       \
                    ((((ks) * 4 + quad) ^ (l15 & 7)) * 8)))
#define BRD(nq, nt, ks)                                                  \
  (*(const short8*)(bs + (wn + (nq) * 32 + (nt) * 16 + l15) * 64 +       \
                    ((((ks) * 4 + quad) ^ (l15 & 7)) * 8)))

  const int nkt = K / 64;  // 16 here
  STG_A(0, 0, 0); STG_A(1, 0, 0); STG_B(0, 0, 0); STG_B(1, 0, 0);

  short8 af[2][4][2];
  short8 bf[2][2];

  for (int kt = 0; kt < nkt; ++kt) {
    const int buf = kt & 1, nbuf = buf ^ 1;
    const int k0n = (kt + 1) * 64;
    const bool pf = (kt + 1 < nkt);
    const unsigned short* as = Asl[buf];
    const unsigned short* bs = Bsl[buf];

    asm volatile("s_waitcnt vmcnt(0)" ::: "memory");
    __builtin_amdgcn_s_barrier();
    __builtin_amdgcn_sched_barrier(0);  // no ds_read hoisted above barrier

    // ---- P1: quadrant (0,0); stage next A-half0 --------------------------
    if (pf) STG_A(0, nbuf, k0n);
#pragma unroll
    for (int mt = 0; mt < 4; ++mt)
#pragma unroll
      for (int ks = 0; ks < 2; ++ks) af[0][mt][ks] = ARD(0, mt, ks);
#pragma unroll
    for (int nt = 0; nt < 2; ++nt)
#pragma unroll
      for (int ks = 0; ks < 2; ++ks) bf[nt][ks] = BRD(0, nt, ks);
    __builtin_amdgcn_s_setprio(1);
#pragma unroll
    for (int mt = 0; mt < 4; ++mt)
#pragma unroll
      for (int nt = 0; nt < 2; ++nt)
#pragma unroll
        for (int ks = 0; ks < 2; ++ks)
          acc[mt][nt] = __builtin_amdgcn_mfma_f32_16x16x32_bf16(
              af[0][mt][ks], bf[nt][ks], acc[mt][nt], 0, 0, 0);
    __builtin_amdgcn_s_setprio(0);

    // ---- P2: quadrant (1,0); stage next A-half1 --------------------------
    if (pf) STG_A(1, nbuf, k0n);
#pragma unroll
    for (int mt = 0; mt < 4; ++mt)
#pragma unroll
      for (int ks = 0; ks < 2; ++ks) af[1][mt][ks] = ARD(1, mt, ks);
    __builtin_amdgcn_s_setprio(1);
#pragma unroll
    for (int mt = 0; mt < 4; ++mt)
#pragma unroll
      for (int nt = 0; nt < 2; ++nt)
#pragma unroll
        for (int ks = 0; ks < 2; ++ks)
          acc[4 + mt][nt] = __builtin_amdgcn_mfma_f32_16x16x32_bf16(
              af[1][mt][ks], bf[nt][ks], acc[4 + mt][nt], 0, 0, 0);
    __builtin_amdgcn_s_setprio(0);

    // ---- P3: quadrant (1,1); stage next B-half0 --------------------------
    if (pf) STG_B(0, nbuf, k0n);
#pragma unroll
    for (int nt = 0; nt < 2; ++nt)
#pragma unroll
      for (int ks = 0; ks < 2; ++ks) bf[nt][ks] = BRD(1, nt, ks);
    __builtin_amdgcn_s_setprio(1);
#pragma unroll
    for (int mt = 0; mt < 4; ++mt)
#pragma unroll
      for (int nt = 0; nt < 2; ++nt)
#pragma unroll
        for (int ks = 0; ks < 2; ++ks)
          acc[4 + mt][2 + nt] = __builtin_amdgcn_mfma_f32_16x16x32_bf16(
              af[1][mt][ks], bf[nt][ks], acc[4 + mt][2 + nt], 0, 0, 0);
    __builtin_amdgcn_s_setprio(0);

    // ---- P4: quadrant (0,1); stage next B-half1 (af0/bf1 held) -----------
    if (pf) STG_B(1, nbuf, k0n);
    __builtin_amdgcn_s_setprio(1);
#pragma unroll
    for (int mt = 0; mt < 4; ++mt)
#pragma unroll
      for (int nt = 0; nt < 2; ++nt)
#pragma unroll
        for (int ks = 0; ks < 2; ++ks)
          acc[mt][2 + nt] = __builtin_amdgcn_mfma_f32_16x16x32_bf16(
              af[0][mt][ks], bf[nt][ks], acc[mt][2 + nt], 0, 0, 0);
    __builtin_amdgcn_s_setprio(0);
  }
#undef STG_A
#undef STG_B
#undef ARD
#undef BRD

  float bv[4];
#pragma unroll
  for (int n = 0; n < 4; ++n)
    bv[n] = bias[col0 + wn + (n >> 1) * 32 + (n & 1) * 16 + l15];

  if (VT && col0 >= 2 * kD) {
    // ---- fused V-transpose epilogue: C^T -> vtb, via SL (verified r9) ----
    __syncthreads();  // all waves done with K-loop LDS reads
#pragma unroll
    for (int m = 0; m < 8; ++m)
#pragma unroll
      for (int n = 0; n < 4; ++n) {
        const int cl = wn + (n >> 1) * 32 + (n & 1) * 16 + l15;
        const int u = (wm >> 2) + (m >> 2) * 16 + (m & 3) * 4 + quad;
        uint2 pk = make_uint2(
            cvtpk2bf(acc[m][n][0] + bv[n], acc[m][n][1] + bv[n]),
            cvtpk2bf(acc[m][n][2] + bv[n], acc[m][n][3] + bv[n]));
        *(uint2*)(SL + cl * 256 + ((u ^ (cl & 15)) << 2)) = pk;
      }
    __syncthreads();
    const int b_ = by >> 3, s0 = (by & 7) * 256;
    const int lhalf = lane >> 5, l31 = lane & 31;
#pragma unroll
    for (int ps = 0; ps < 16; ++ps) {
      const int cl = ps * 16 + w * 2 + lhalf;
      uint2 v0 = *(const uint2*)(SL + cl * 256 +
                                 (((l31 * 2) ^ (cl & 15)) << 2));
      uint2 v1 = *(const uint2*)(SL + cl * 256 +
                                 (((l31 * 2 + 1) ^ (cl & 15)) << 2));
      uint4 vv = make_uint4(v0.x, v0.y, v1.x, v1.y);
      unsigned short* gd =
          vtbp + (size_t)(b_ * 1024 + col0 - 2 * kD + cl) * kS + s0 + l31 * 8;
      *(uint4*)gd = vv;
    }
    return;
  }

  const float sc = (QSCALE && col0 < kD) ? kQscale : 1.0f;
#pragma unroll
  for (int m = 0; m < 8; ++m)
#pragma unroll
    for (int i = 0; i < 4; ++i) {
      const size_t r =
          (size_t)(row0 + wm + (m >> 2) * 64 + (m & 3) * 16 + quad * 4 + i);
#pragma unroll
      for (int n = 0; n < 4; ++n) {
        float v = (acc[m][n][i] + bv[n]) * sc;
        const size_t cidx =
            r * (size_t)ldc + col0 + wn + (n >> 1) * 32 + (n & 1) * 16 + l15;
        if (OUT_BF16) ((unsigned short*)Cp)[cidx] = f2bf(v);
        else          ((float*)Cp)[cidx] = v;
      }
    }
}

// ---------------------------------------------------------------------------
// 128x128 / BK=32 / 256-thread MFMA GEMM — round-0 version, verified passing.
// ---------------------------------------------------------------------------
template <bool OUT_BF16, bool QSCALE>
__global__ __launch_bounds__(256) void gemm_mfma_128(
    const unsigned short* __restrict__ A, int lda,
    const unsigned short* __restrict__ Bt, int ldb,
    const float* __restrict__ bias, void* __restrict__ Cp, int ldc, int K) {
  __shared__ unsigned short As[2][4096];  // 16 KB
  __shared__ unsigned short Bs[2][4096];  // 16 KB
  const int t = threadIdx.x;
  const int lane = t & 63, l15 = lane & 15, quad = lane >> 4, w = t >> 6;

  const int nwg = gridDim.x * gridDim.y;
  int bid = blockIdx.y * gridDim.x + blockIdx.x;
  if ((nwg & 7) == 0) bid = (bid & 7) * (nwg >> 3) + (bid >> 3);
  const int bx = bid % gridDim.x, by = bid / gridDim.x;

  const int row0 = by * 128, col0 = bx * 128;
  const int wm = (w & 1) * 64, wn = (w >> 1) * 64;

  f32x4 acc[4][4] = {};

  const int q1 = t, q2 = t + 256;
  const unsigned short* a1 = A  + (size_t)(row0 + (q1 & 127)) * lda + (q1 >> 7) * 8;
  const unsigned short* a2 = A  + (size_t)(row0 + (q2 & 127)) * lda + (q2 >> 7) * 8;
  const unsigned short* b1 = Bt + (size_t)(col0 + (q1 & 127)) * ldb + (q1 >> 7) * 8;
  const unsigned short* b2 = Bt + (size_t)(col0 + (q2 & 127)) * ldb + (q2 >> 7) * 8;

  const int nIter = K / 32;
  async16(a1, As[0] + q1 * 8);
  async16(a2, As[0] + q2 * 8);
  async16(b1, Bs[0] + q1 * 8);
  async16(b2, Bs[0] + q2 * 8);

  for (int it = 0; it < nIter; ++it) {
    __syncthreads();
    const int cb = it & 1, nb = cb ^ 1;
    if (it + 1 < nIter) {
      const int k0 = (it + 1) * 32;
      async16(a1 + k0, As[nb] + q1 * 8);
      async16(a2 + k0, As[nb] + q2 * 8);
      async16(b1 + k0, Bs[nb] + q1 * 8);
      async16(b2 + k0, Bs[nb] + q2 * 8);
    }
    short8 af[4], bf[4];
#pragma unroll
    for (int mt = 0; mt < 4; ++mt)
      af[mt] = *(const short8*)(As[cb] + (quad * 128 + wm + mt * 16 + l15) * 8);
#pragma unroll
    for (int nt = 0; nt < 4; ++nt)
      bf[nt] = *(const short8*)(Bs[cb] + (quad * 128 + wn + nt * 16 + l15) * 8);
#pragma unroll
    for (int mt = 0; mt < 4; ++mt)
#pragma unroll
      for (int nt = 0; nt < 4; ++nt)
        acc[mt][nt] = __builtin_amdgcn_mfma_f32_16x16x32_bf16(
            af[mt], bf[nt], acc[mt][nt], 0, 0, 0);
  }

  const float sc = (QSCALE && col0 < kD) ? kQscale : 1.0f;
  float bv[4];
#pragma unroll
  for (int nt = 0; nt < 4; ++nt) bv[nt] = bias[col0 + wn + nt * 16 + l15];
#pragma unroll
  for (int mt = 0; mt < 4; ++mt)
#pragma unroll
    for (int i = 0; i < 4; ++i) {
      const size_t r = (size_t)(row0 + wm + mt * 16 + quad * 4 + i);
#pragma unroll
      for (int nt = 0; nt < 4; ++nt) {
        float v = (acc[mt][nt][i] + bv[nt]) * sc;
        const size_t cidx = r * (size_t)ldc + col0 + wn + nt * 16 + l15;
        if (OUT_BF16) ((unsigned short*)Cp)[cidx] = f2bf(v);
        else          ((float*)Cp)[cidx] = v;
      }
    }
}

// ---------------------------------------------------------------------------
// MFMA flash attention — round-11: QBLK=128 (8 waves, 512 threads).
// Per-wave inner code is IDENTICAL to the verified round-7 kernel (each wave
// owns 16 q-rows); only block geometry changes: 8 waves share each K/V tile,
// halving per-(b,h) K/V staging redundancy (16x -> 8x) and halving barrier
// events per CU. Grid 512 x 512thr = 2 blocks/CU (48 KB LDS, ~52 VGPR).
// Pair balance: halves qt=pr and 15-pr, ntiles = 2qt+2 -> 34 tiles/block
// for every block. Waves 0-3 skip the final fully-masked tile (wave-uniform
// act guard; barrier outside).
// ---------------------------------------------------------------------------
__global__ __launch_bounds__(512, 4) void flash_attn_mfma(
    unsigned short* __restrict__ qkvb, const unsigned short* __restrict__ vtb,
    const int* __restrict__ cflag) {
  __shared__ unsigned short QP[8192];     // Q then P: [dc 0..7][q 0..127][8] 16 KB
  __shared__ unsigned short Ks[2][4096];  // K dbuf: [dc 0..7][key 0..63][8] 16 KB
  __shared__ unsigned short Vt[2][4096];  // V dbuf: [kc 0..7][d 0..63][8]   16 KB

  const int lin = blockIdx.x;
  const int pr = lin >> 6;                          // 0..7 (pair id)
  const int g  = ((lin >> 3) & 7) * 8 + (lin & 7);  // 0..63, XCD-grouped
  const int h = g & 15, b = g >> 4;
  const int t = threadIdx.x;
  const int lane = t & 63, l15 = lane & 15, quad = lane >> 4, w = t >> 6;
  const bool causal = (*cflag) != 0;

  unsigned short* qbase = qkvb + (size_t)(b * kS) * k3D + h * kDH;
  const unsigned short* vbase = vtb + (size_t)((b * kH + h) * kDH) * kS;

  for (int half = 0; half < 2; ++half) {
    const int qt = half ? (15 - pr) : pr;
    const int q0 = qt * 128;
    const int ntiles = causal ? (2 * qt + 2) : 32;

    // ---- prologue: stage Q (1024 chunks, 2/thread) + K0 + V0 (1/thread)
    async16(qbase + (size_t)(q0 + (t & 127)) * k3D + (t >> 7) * 8, QP + t * 8);
    async16(qbase + (size_t)(q0 + ((t + 512) & 127)) * k3D +
                ((t + 512) >> 7) * 8,
            QP + (t + 512) * 8);
    async16(qbase + kD + (size_t)(t & 63) * k3D + (t >> 6) * 8, Ks[0] + t * 8);
    async16(vbase + (size_t)(t & 63) * kS + (t >> 6) * 8, Vt[0] + t * 8);
    __syncthreads();  // drains Q + K0 + V0

    // hoist Q fragments to registers — QP becomes the P buffer afterwards
    short8 bq[2];
#pragma unroll
    for (int kf = 0; kf < 2; ++kf)
      bq[kf] = *(const short8*)(
          QP + ((kf * 4 + quad) * 128 + w * 16 + l15) * 8);

    f32x4 O[4] = {};                  // [d-tile ntd]; q row = w*16+quad*4+i
    float m_i = -3.0e38f, l_i = 0.f;  // per q (q = w*16+l15)
    const int gqw = q0 + w * 16;      // wave's min q-row

    for (int kt = 0; kt < ntiles; ++kt) {
      const int cb = kt & 1, nb = cb ^ 1;
      const int kk0 = kt * 64;

      // ---- issue K/V(kt+1) into spare buffer: full-iteration cover
      if (kt + 1 < ntiles) {
        const int kn = kk0 + 64;
        async16(qbase + kD + (size_t)(kn + (t & 63)) * k3D + (t >> 6) * 8,
                Ks[nb] + t * 8);
        async16(vbase + (size_t)(t & 63) * kS + kn + (t >> 6) * 8,
                Vt[nb] + t * 8);
      }

      // wave-uniform: skip tiles entirely above the causal diagonal
      const bool act = !causal || (kk0 <= gqw + 15);
      if (act) {
        // ---- S^T = K·Q^T: key = kk0+mt*16+quad*4+reg, q = gqw+l15
        f32x4 s[4];
        __builtin_amdgcn_s_setprio(1);
#pragma unroll
        for (int mt = 0; mt < 4; ++mt) {
          short8 a0 =
              *(const short8*)(Ks[cb] + ((quad)*64 + mt * 16 + l15) * 8);
          short8 a1 =
              *(const short8*)(Ks[cb] + ((4 + quad) * 64 + mt * 16 + l15) * 8);
          f32x4 z = {};
          z = __builtin_amdgcn_mfma_f32_16x16x32_bf16(a0, bq[0], z, 0, 0, 0);
          z = __builtin_amdgcn_mfma_f32_16x16x32_bf16(a1, bq[1], z, 0, 0, 0);
          s[mt] = z;
        }
        __builtin_amdgcn_s_setprio(0);

        // ---- online softmax (log2 domain; diagonal-crossing tiles masked)
        const int gq = gqw + l15;
        if (causal && kk0 + 63 > gqw) {
#pragma unroll
          for (int mt = 0; mt < 4; ++mt)
#pragma unroll
            for (int i = 0; i < 4; ++i)
              if (kk0 + mt * 16 + quad * 4 + i > gq) s[mt][i] = -3.0e38f;
        }
        float mx = -3.0e38f;
#pragma unroll
        for (int mt = 0; mt < 4; ++mt)
#pragma unroll
          for (int i = 0; i < 4; ++i) mx = fmaxf(mx, s[mt][i]);
        mx = fmaxf(mx, __shfl_xor(mx, 16));
        mx = fmaxf(mx, __shfl_xor(mx, 32));

        // defer-max (T13): only rescale when the running max grew by > 8
        if (!__all(mx <= m_i + 8.0f)) {
          const float mn = fmaxf(m_i, mx);
          const float alpha = exp2v(m_i - mn);
          m_i = mn;
          l_i *= alpha;
#pragma unroll
          for (int i = 0; i < 4; ++i) {
            const float a = __shfl(alpha, quad * 4 + i);
#pragma unroll
            for (int ntd = 0; ntd < 4; ++ntd) O[ntd][i] *= a;
          }
        }

        float p[4][4];
        float rs = 0.f;
#pragma unroll
        for (int mt = 0; mt < 4; ++mt)
#pragma unroll
          for (int i = 0; i < 4; ++i) {
            p[mt][i] = exp2v(s[mt][i] - m_i);
            rs += p[mt][i];
          }
        rs += __shfl_xor(rs, 16);
        rs += __shfl_xor(rs, 32);
        l_i += rs;

        // packed P store: 4 consecutive keys at local q-row w*16+l15
#pragma unroll
        for (int mt = 0; mt < 4; ++mt) {
          uint2 pk = make_uint2(cvtpk2bf(p[mt][0], p[mt][1]),
                                cvtpk2bf(p[mt][2], p[mt][3]));
          *(uint2*)(QP + ((mt * 2 + (quad >> 1)) * 128 + w * 16 + l15) * 8 +
                    (quad & 1) * 4) = pk;
        }

        // ---- O += P·V (P rows wave-private; compiler orders write->read)
        __builtin_amdgcn_s_setprio(1);
#pragma unroll
        for (int kf = 0; kf < 2; ++kf) {
          short8 aP = *(const short8*)(
              QP + ((kf * 4 + quad) * 128 + w * 16 + l15) * 8);
#pragma unroll
          for (int ntd = 0; ntd < 4; ++ntd) {
            short8 bV = *(const short8*)(
                Vt[cb] + ((kf * 4 + quad) * 64 + ntd * 16 + l15) * 8);
            O[ntd] = __builtin_amdgcn_mfma_f32_16x16x32_bf16(
                aP, bV, O[ntd], 0, 0, 0);
          }
        }
        __builtin_amdgcn_s_setprio(0);
      }

      // single barrier per k-tile: reads of buffer cb done + K/V(kt+1) landed
      __syncthreads();
    }

    // ---- epilogue: /l, bf16, overwrite own Q slots
#pragma unroll
    for (int i = 0; i < 4; ++i) {
      const float linv = 1.0f / __shfl(l_i, quad * 4 + i);
      unsigned short* dst =
          qbase + (size_t)(q0 + w * 16 + quad * 4 + i) * k3D;
#pragma unroll
      for (int ntd = 0; ntd < 4; ++ntd)
        dst[ntd * 16 + l15] = f2bf(O[ntd][i] * linv);
    }
  }
}

// ---------------------------------------------------------------------------
extern "C" void kernel_launch(void* const* d_in, const int* in_sizes, int n_in,
                              void* d_out, int out_size, void* d_ws,
                              size_t ws_size, hipStream_t stream) {
  const float* x     = (const float*)d_in[0];
  const float* w_in  = (const float*)d_in[1];
  const float* b_in  = (const float*)d_in[2];
  const float* w_out = (const float*)d_in[3];
  const float* b_out = (const float*)d_in[4];
  const int*   cfl   = (const int*)d_in[5];
  float* out = (float*)d_out;

  // workspace layout (all 16B-aligned), total 92.3 MB
  char* ws = (char*)d_ws;
  unsigned short* qkvb = (unsigned short*)(ws);              // 8192x3072 bf16 = 48 MB
  unsigned short* xb   = (unsigned short*)(ws + 50331648);   // 8192x1024 bf16 = 16 MB
  unsigned short* wib  = (unsigned short*)(ws + 67108864);   // 3072x1024 bf16 =  6 MB
  unsigned short* wob  = (unsigned short*)(ws + 73400320);   // 1024x1024 bf16 =  2 MB
  unsigned short* vtb  = (unsigned short*)(ws + 75497472);   // [b,h,d,s] bf16 = 16 MB

  // 0) all three fp32->bf16 conversions in one launch
  cvt_bf16_3<<<(kM * kD + k3D * kD + kD * kD) / 4 / 256, 256, 0, stream>>>(
      x, w_in, w_out, xb, wib, wob);

  // 1) qkv = x @ w_in^T + b_in (bf16 out; Q cols pre-scaled by 0.125*log2e).
  //    Round-9 verified BK=64 / 128 KB / (512,2). V-column blocks write
  //    TRANSPOSED directly to vtb (fused v_transpose).
  gemm_mfma_256<true, true, true><<<dim3(k3D / 256, kM / 256), 512, 0, stream>>>(
      xb, kD, wib, kD, b_in, qkvb, k3D, kD, vtb);

  // 2) flash attention (QBLK=128, 8 waves; pair-balanced, XCD-grouped,
  //    double-buffered K/V): grid 512 x 512 threads = 2 blocks/CU
  flash_attn_mfma<<<dim3(8 * kH * kB), 512, 0, stream>>>(qkvb, vtb, cfl);

  // 3) out = attn @ w_out^T + b_out (fp32 out; A rows inside qkvb, lda=3072)
  gemm_mfma_128<false, false><<<dim3(kD / 128, kM / 128), 256, 0, stream>>>(
      qkvb, k3D, wob, kD, b_out, out, kD, kD);
}